// Round 13
// baseline (834.439 us; speedup 1.0000x reference)
//
#include <hip/hip_runtime.h>
#include <hip/hip_cooperative_groups.h>

namespace cg = cooperative_groups;

// Problem: b=4, c=256, ci=128, h=w=64 (HW=4096), field=7, kk=49. fp32 I/O.
//
// SINGLE cooperative kernel (512 blocks x 256 thr, 2 blocks/CU co-resident),
// 6 phases separated by grid.sync() — replaces r12's 6 dispatches whose
// ~15 us/boundary drain dominated (accounting r7/r8/r12). Phase bodies are
// the r12-verified kernels, re-indexed as grid-stride unit loops:
//  P1 prep: x -> xp_hi/lo packed fragments; w3/wm hi/lo packed; zero planes.
//  P2 conv3: split-bf16 MFMA (24 MFMA : 12 loads per kb), region per unit;
//     phi/g -> padded planes, theta -> [p][cc] bf16.
//  P3 scores: segmented flat-decode gather, wave per pixel.
//  P4 softmax stats: m, inv per (b,j,t).
//  P5 aggregate: attn = exp(sc-m)*inv inline; segmented gather; y packed.
//  P6 maskconv: split-w MFMA + residual -> out fp32.
//
// Padded planes: [b][c0][70][72] bf16, data (py,px) at (py+3,px+4), zero
// borders; patch addr for F -> (ch=F>>12, p=F&4095):
//   a = OFF(ch) + p + 8*(p>>6), OFF(ch) = c0*5040 + kh*72 + kw + 1.
// MFMA frag layouts (r10/11-verified): fragment = 512 ush, lane ln reads
// 16 B at frag_base + ln*16; C/D col=lane&15, row=quad*4+reg.
//
// ws layout (ushort units): A_phi@0 (2,580,480) | A_g@2,580,480 (2,580,480)
// | y_p@5,160,960 (2,097,152) | theta@7,258,112 (2,097,152) | scores(f32)
// @9,355,264 | xp_hi@11,452,416 | xp_lo@15,646,720 | w3p_hi@19,841,024 |
// w3p_lo@19,939,328 | wmp_hi@20,037,632 | wmp_lo@20,070,400 |
// m@20,103,168 | inv@20,128,256   => ~40.3 MB

#define PLANE    5040
#define A_BATCH  645120
#define GRID     512

#define OFF_APHI 0
#define OFF_AG   2580480
#define OFF_YP   5160960
#define OFF_TH   7258112
#define OFF_SC   9355264
#define OFF_XPH  11452416
#define OFF_XPL  15646720
#define OFF_W3H  19841024
#define OFF_W3L  19939328
#define OFF_WMH  20037632
#define OFF_WML  20070400
#define OFF_M    20103168
#define OFF_INV  20128256

typedef __attribute__((ext_vector_type(8))) short short8;
typedef __attribute__((ext_vector_type(4))) float floatx4;

__device__ __forceinline__ float bf2f(unsigned short u) {
    union { unsigned int i; float f; } v; v.i = ((unsigned int)u) << 16; return v.f;
}
__device__ __forceinline__ unsigned short f2bf(float f) {
    union { float f; unsigned int i; } v; v.f = f;
    unsigned int r = v.i + 0x7FFFu + ((v.i >> 16) & 1u);
    return (unsigned short)(r >> 16);
}

__global__ void __launch_bounds__(256, 2) mono_kernel(
    const float* x,
    const float* w_phi,
    const float* w_theta,
    const float* w_g,
    const float* w_mask,
    unsigned short* ws_u,
    float* out_f)
{
    cg::grid_group grid = cg::this_grid();
    const int tid = threadIdx.x;
    const int w   = tid >> 6;
    const int ln  = tid & 63;
    const int lm  = ln & 15;
    const int quad = ln >> 4;

    unsigned short* A_phi = ws_u + OFF_APHI;
    unsigned short* A_g   = ws_u + OFF_AG;
    unsigned short* y_p   = ws_u + OFF_YP;
    unsigned short* th_u  = ws_u + OFF_TH;
    float*          sc_f  = (float*)(ws_u + OFF_SC);
    unsigned short* xp_hi = ws_u + OFF_XPH;
    unsigned short* xp_lo = ws_u + OFF_XPL;
    unsigned short* w3p_hi= ws_u + OFF_W3H;
    unsigned short* w3p_lo= ws_u + OFF_W3L;
    unsigned short* wmp_hi= ws_u + OFF_WMH;
    unsigned short* wmp_lo= ws_u + OFF_WML;
    float*          m_f   = (float*)(ws_u + OFF_M);
    float*          inv_f = (float*)(ws_u + OFF_INV);

    __shared__ __align__(16) float smem[64 * 65];   // 16.6 KB, re-aliased

    // ================= P1: prep =================
    for (int u = blockIdx.x; u < 1152; u += GRID) {
        __syncthreads();
        if (u < 1024) {
            const int b  = u >> 8;
            const int kt = (u >> 6) & 3;
            const int pt = u & 63;
            float (*tile)[65] = reinterpret_cast<float(*)[65]>(smem);
            #pragma unroll
            for (int i = 0; i < 16; ++i) {
                int lin = tid + i * 256;
                int kk = lin >> 6, pp = lin & 63;
                tile[kk][pp] = x[(b * 256 + kt * 64 + kk) * 4096 + pt * 64 + pp];
            }
            __syncthreads();
            #pragma unroll
            for (int i = 0; i < 16; ++i) {
                int lin = tid + i * 256;
                int frag = lin >> 9;
                int idx  = lin & 511;
                int kbL  = frag >> 2;
                int ptL  = frag & 3;
                int j    = idx & 7;
                int n    = (idx >> 3) & 15;
                int qd   = idx >> 7;
                float f = tile[kbL * 32 + qd * 8 + j][ptL * 16 + n];
                unsigned short h = f2bf(f);
                int addr = ((b * 8 + kt * 2 + kbL) * 256 + pt * 4 + ptL) * 512 + idx;
                xp_hi[addr] = h;
                xp_lo[addr] = f2bf(f - bf2f(h));
            }
        } else {
            const int wid = (u - 1024) * 256 + tid;   // 0..32767
            for (int e = wid; e < 98304; e += 32768) {
                int frag = e >> 9;
                int idx  = e & 511;
                int nt16 = frag >> 3, kb = frag & 7;
                int j = idx & 7, m = (idx >> 3) & 15, qd = idx >> 7;
                int n = nt16 * 16 + m;
                int k = kb * 32 + qd * 8 + j;
                float v = (n < 128) ? w_phi[n * 256 + k]
                        : (n < 256) ? w_theta[(n - 128) * 256 + k]
                                    : w_g[(n - 256) * 256 + k];
                unsigned short h = f2bf(v);
                w3p_hi[e] = h;
                w3p_lo[e] = f2bf(v - bf2f(h));
            }
            {
                int e = wid;
                int frag = e >> 9;
                int idx  = e & 511;
                int ot16 = frag >> 2, kb = frag & 3;
                int j = idx & 7, m = (idx >> 3) & 15, qd = idx >> 7;
                float v = w_mask[(ot16 * 16 + m) * 128 + kb * 32 + qd * 8 + j];
                unsigned short h = f2bf(v);
                wmp_hi[e] = h;
                wmp_lo[e] = f2bf(v - bf2f(h));
            }
            uint4* zr = reinterpret_cast<uint4*>(A_phi);
            const uint4 z = make_uint4(0u, 0u, 0u, 0u);
            for (int i = wid; i < 645120; i += 32768) zr[i] = z;
        }
    }
    __threadfence();
    grid.sync();

    // ================= P2: conv3 MFMA =================
    for (int u = blockIdx.x; u < 768; u += GRID) {
        const int bx = u & 63;       // px 64-tile; py = bx
        const int v  = u >> 6;       // 0..11
        const int nt = v % 3;        // region
        const int b  = v / 3;
        const int nt16a = nt * 8 + w;
        const int nt16b = nt * 8 + 4 + w;
        const int lnofs = ln * 8;

        floatx4 accA[4] = {{0.f,0.f,0.f,0.f},{0.f,0.f,0.f,0.f},
                           {0.f,0.f,0.f,0.f},{0.f,0.f,0.f,0.f}};
        floatx4 accB[4] = {{0.f,0.f,0.f,0.f},{0.f,0.f,0.f,0.f},
                           {0.f,0.f,0.f,0.f},{0.f,0.f,0.f,0.f}};

        #pragma unroll
        for (int kb = 0; kb < 8; ++kb) {
            const int aoffA = (nt16a * 8 + kb) * 512 + lnofs;
            const int aoffB = (nt16b * 8 + kb) * 512 + lnofs;
            const int boff  = ((b * 8 + kb) * 256 + bx * 4) * 512 + lnofs;
            short8 ahA = *reinterpret_cast<const short8*>(w3p_hi + aoffA);
            short8 alA = *reinterpret_cast<const short8*>(w3p_lo + aoffA);
            short8 ahB = *reinterpret_cast<const short8*>(w3p_hi + aoffB);
            short8 alB = *reinterpret_cast<const short8*>(w3p_lo + aoffB);
            short8 bh[4], bl[4];
            #pragma unroll
            for (int ct = 0; ct < 4; ++ct) {
                bh[ct] = *reinterpret_cast<const short8*>(xp_hi + boff + ct * 512);
                bl[ct] = *reinterpret_cast<const short8*>(xp_lo + boff + ct * 512);
            }
            #pragma unroll
            for (int ct = 0; ct < 4; ++ct) {
                accA[ct] = __builtin_amdgcn_mfma_f32_16x16x32_bf16(ahA, bh[ct], accA[ct], 0, 0, 0);
                accA[ct] = __builtin_amdgcn_mfma_f32_16x16x32_bf16(ahA, bl[ct], accA[ct], 0, 0, 0);
                accA[ct] = __builtin_amdgcn_mfma_f32_16x16x32_bf16(alA, bh[ct], accA[ct], 0, 0, 0);
                accB[ct] = __builtin_amdgcn_mfma_f32_16x16x32_bf16(ahB, bh[ct], accB[ct], 0, 0, 0);
                accB[ct] = __builtin_amdgcn_mfma_f32_16x16x32_bf16(ahB, bl[ct], accB[ct], 0, 0, 0);
                accB[ct] = __builtin_amdgcn_mfma_f32_16x16x32_bf16(alB, bh[ct], accB[ct], 0, 0, 0);
            }
        }

        const int py = bx;
        if (nt == 1) {
            #pragma unroll
            for (int ct = 0; ct < 4; ++ct) {
                const int p = bx * 64 + ct * 16 + lm;
                #pragma unroll
                for (int reg = 0; reg < 4; ++reg) {
                    const int r = w * 16 + quad * 4 + reg;
                    th_u[(b * 4096 + p) * 128 + r]      = f2bf(accA[ct][reg]);
                    th_u[(b * 4096 + p) * 128 + r + 64] = f2bf(accB[ct][reg]);
                }
            }
        } else {
            unsigned short* A = (nt == 0) ? A_phi : A_g;
            #pragma unroll
            for (int ct = 0; ct < 4; ++ct) {
                const int pxx = ct * 16 + lm;
                #pragma unroll
                for (int reg = 0; reg < 4; ++reg) {
                    const int r = w * 16 + quad * 4 + reg;
                    A[b * A_BATCH + r * PLANE + (py + 3) * 72 + pxx + 4] =
                        f2bf(accA[ct][reg]);
                    A[b * A_BATCH + (r + 64) * PLANE + (py + 3) * 72 + pxx + 4] =
                        f2bf(accB[ct][reg]);
                }
            }
        }
    }
    __threadfence();
    grid.sync();

    // ================= P3: scores =================
    // th rows are wave-private (wave w writes/reads th[w] only): no barriers.
    {
        float (*th)[128] = reinterpret_cast<float(*)[128]>(smem);
        for (int u = blockIdx.x; u < 4096; u += GRID) {
            const int b = u >> 10;
            const int s = (u & 1023) * 4 + w;

            {
                const unsigned short* tb = th_u + (b * 4096 + s) * 128;
                th[w][ln]      = bf2f(tb[ln]);
                th[w][ln + 64] = bf2f(tb[ln + 64]);
            }

            const unsigned short* Ab = A_phi + b * A_BATCH;
            const int base  = s * 6272;
            const int ch_lo = base >> 12;
            const unsigned B1 = (unsigned)(ch_lo + 1) << 12;
            const unsigned B2 = (unsigned)(ch_lo + 2) << 12;
            const int d1 = (int)B1 - base;
            const int d2 = d1 + 4096;

            int A1 = d1 / 49;
            int A2 = (d1 + 48) / 49;
            int C1 = d2 / 49;        if (C1 > 128) C1 = 128;
            int C2 = (d2 + 48) / 49; if (C2 > 128) C2 = 128;

            unsigned OFFv[3];
            #pragma unroll
            for (int i = 0; i < 3; ++i) {
                int ch = ch_lo + i;
                int c0 = ch / 49; if (c0 > 127) c0 = 127;
                int rr = ch - c0 * 49;
                int kh = rr / 7;
                int kw = rr - kh * 7;
                OFFv[i] = (unsigned)(c0 * PLANE + kh * 72 + kw + 1);
            }

            unsigned F = (unsigned)(base + ln);
            float acc = 0.f;
            {
                const unsigned OFF_ = OFFv[0];
                #pragma unroll 4
                for (int cc = 0; cc < A1; ++cc) {
                    unsigned p = F & 4095u;
                    unsigned a = OFF_ + p + ((p >> 6) << 3);
                    acc = fmaf(th[w][cc], bf2f(Ab[a]), acc);
                    F += 49u;
                }
            }
            for (int cc = A1; cc < A2; ++cc) {
                unsigned OFF_ = (F >= B1) ? OFFv[1] : OFFv[0];
                unsigned p = F & 4095u;
                unsigned a = OFF_ + p + ((p >> 6) << 3);
                acc = fmaf(th[w][cc], bf2f(Ab[a]), acc);
                F += 49u;
            }
            {
                const unsigned OFF_ = OFFv[1];
                #pragma unroll 4
                for (int cc = A2; cc < C1; ++cc) {
                    unsigned p = F & 4095u;
                    unsigned a = OFF_ + p + ((p >> 6) << 3);
                    acc = fmaf(th[w][cc], bf2f(Ab[a]), acc);
                    F += 49u;
                }
            }
            for (int cc = C1; cc < C2; ++cc) {
                unsigned OFF_ = (F >= B2) ? OFFv[2] : OFFv[1];
                unsigned p = F & 4095u;
                unsigned a = OFF_ + p + ((p >> 6) << 3);
                acc = fmaf(th[w][cc], bf2f(Ab[a]), acc);
                F += 49u;
            }
            {
                const unsigned OFF_ = OFFv[2];
                #pragma unroll 4
                for (int cc = C2; cc < 128; ++cc) {
                    unsigned p = F & 4095u;
                    unsigned a = OFF_ + p + ((p >> 6) << 3);
                    acc = fmaf(th[w][cc], bf2f(Ab[a]), acc);
                    F += 49u;
                }
            }
            if (ln < 49) sc_f[(b * 4096 + s) * 64 + ln] = acc;
        }
    }
    __threadfence();
    grid.sync();

    // ================= P4: softmax stats =================
    {
        float (*tile)[52] = reinterpret_cast<float(*)[52]>(smem);
        for (int u = blockIdx.x; u < 256; u += GRID) {
            const int b = u >> 6;
            const int j = u & 63;
            __syncthreads();
            #pragma unroll
            for (int it = 0; it < 16; ++it) {
                int i = it * 4 + w;
                if (ln < 49) tile[i][ln] = sc_f[(b * 4096 + i * 64 + j) * 64 + ln];
            }
            __syncthreads();
            if (tid < 49) {
                float m = -3.4e38f;
                #pragma unroll 8
                for (int i = 0; i < 64; ++i) m = fmaxf(m, tile[i][tid]);
                float sum = 0.f;
                #pragma unroll 8
                for (int i = 0; i < 64; ++i) sum += __expf(tile[i][tid] - m);
                m_f[(b * 64 + j) * 49 + tid]   = m;
                inv_f[(b * 64 + j) * 49 + tid] = 1.f / sum;
            }
        }
    }
    __threadfence();
    grid.sync();

    // ================= P5: aggregate =================
    {
        float (*at)[52] = reinterpret_cast<float(*)[52]>(smem);
        const int pix = tid >> 7;
        const int cc  = tid & 127;
        for (int u = blockIdx.x; u < 8192; u += GRID) {
            const int b = u >> 11;
            const int s = (u & 2047) * 2 + pix;
            __syncthreads();
            if (cc < 49) {
                const int j = s & 63;
                float sc = sc_f[(b * 4096 + s) * 64 + cc];
                float m  = m_f[(b * 64 + j) * 49 + cc];
                float iv = inv_f[(b * 64 + j) * 49 + cc];
                at[pix][cc] = __expf(sc - m) * iv;
            }
            __syncthreads();

            const unsigned short* Ab = A_g + b * A_BATCH;
            const int base  = s * 6272;
            const int ch_lo = base >> 12;
            const unsigned B1 = (unsigned)(ch_lo + 1) << 12;
            const unsigned B2 = (unsigned)(ch_lo + 2) << 12;
            const int d1 = (int)B1 - base;
            const int d2 = d1 + 4096;

            int A1 = d1 >> 7;
            int A2 = (d1 + 127) >> 7;
            int C1 = d2 >> 7;          if (C1 > 49) C1 = 49;
            int C2 = (d2 + 127) >> 7;  if (C2 > 49) C2 = 49;
            if (A1 > 49) A1 = 49;
            if (A2 > 49) A2 = 49;

            unsigned OFFv[3];
            #pragma unroll
            for (int i = 0; i < 3; ++i) {
                int ch = ch_lo + i;
                int c0 = ch / 49; if (c0 > 127) c0 = 127;
                int rr = ch - c0 * 49;
                int kh = rr / 7;
                int kw = rr - kh * 7;
                OFFv[i] = (unsigned)(c0 * PLANE + kh * 72 + kw + 1);
            }

            unsigned F = (unsigned)(base + cc);
            float acc = 0.f;
            {
                const unsigned OFF_ = OFFv[0];
                #pragma unroll 4
                for (int t = 0; t < A1; ++t) {
                    unsigned p = F & 4095u;
                    unsigned a = OFF_ + p + ((p >> 6) << 3);
                    acc = fmaf(at[pix][t], bf2f(Ab[a]), acc);
                    F += 128u;
                }
            }
            for (int t = A1; t < A2; ++t) {
                unsigned OFF_ = (F >= B1) ? OFFv[1] : OFFv[0];
                unsigned p = F & 4095u;
                unsigned a = OFF_ + p + ((p >> 6) << 3);
                acc = fmaf(at[pix][t], bf2f(Ab[a]), acc);
                F += 128u;
            }
            {
                const unsigned OFF_ = OFFv[1];
                #pragma unroll 4
                for (int t = A2; t < C1; ++t) {
                    unsigned p = F & 4095u;
                    unsigned a = OFF_ + p + ((p >> 6) << 3);
                    acc = fmaf(at[pix][t], bf2f(Ab[a]), acc);
                    F += 128u;
                }
            }
            for (int t = C1; t < C2; ++t) {
                unsigned OFF_ = (F >= B2) ? OFFv[2] : OFFv[1];
                unsigned p = F & 4095u;
                unsigned a = OFF_ + p + ((p >> 6) << 3);
                acc = fmaf(at[pix][t], bf2f(Ab[a]), acc);
                F += 128u;
            }
            {
                const unsigned OFF_ = OFFv[2];
                for (int t = C2; t < 49; ++t) {
                    unsigned p = F & 4095u;
                    unsigned a = OFF_ + p + ((p >> 6) << 3);
                    acc = fmaf(at[pix][t], bf2f(Ab[a]), acc);
                    F += 128u;
                }
            }

            const int kb = cc >> 5, k32 = cc & 31;
            const int qd = k32 >> 3, j = k32 & 7;
            const int pt16 = s >> 4, n = s & 15;
            y_p[((b * 4 + kb) * 256 + pt16) * 512 + (qd * 16 + n) * 8 + j] = f2bf(acc);
        }
    }
    __threadfence();
    grid.sync();

    // ================= P6: maskconv MFMA =================
    for (int u = blockIdx.x; u < 512; u += GRID) {
        const int bx = u & 63;
        const int v  = u >> 6;       // 0..7
        const int ot = v & 1;
        const int b  = v >> 1;
        const int ot16a = ot * 8 + w;
        const int ot16b = ot * 8 + 4 + w;
        const int lnofs = ln * 8;

        floatx4 accA[4] = {{0.f,0.f,0.f,0.f},{0.f,0.f,0.f,0.f},
                           {0.f,0.f,0.f,0.f},{0.f,0.f,0.f,0.f}};
        floatx4 accB[4] = {{0.f,0.f,0.f,0.f},{0.f,0.f,0.f,0.f},
                           {0.f,0.f,0.f,0.f},{0.f,0.f,0.f,0.f}};

        #pragma unroll
        for (int kb = 0; kb < 4; ++kb) {
            const int aoffA = (ot16a * 4 + kb) * 512 + lnofs;
            const int aoffB = (ot16b * 4 + kb) * 512 + lnofs;
            const int boff  = ((b * 4 + kb) * 256 + bx * 4) * 512 + lnofs;
            short8 ahA = *reinterpret_cast<const short8*>(wmp_hi + aoffA);
            short8 alA = *reinterpret_cast<const short8*>(wmp_lo + aoffA);
            short8 ahB = *reinterpret_cast<const short8*>(wmp_hi + aoffB);
            short8 alB = *reinterpret_cast<const short8*>(wmp_lo + aoffB);
            short8 bfv[4];
            #pragma unroll
            for (int ct = 0; ct < 4; ++ct)
                bfv[ct] = *reinterpret_cast<const short8*>(y_p + boff + ct * 512);
            #pragma unroll
            for (int ct = 0; ct < 4; ++ct) {
                accA[ct] = __builtin_amdgcn_mfma_f32_16x16x32_bf16(ahA, bfv[ct], accA[ct], 0, 0, 0);
                accA[ct] = __builtin_amdgcn_mfma_f32_16x16x32_bf16(alA, bfv[ct], accA[ct], 0, 0, 0);
                accB[ct] = __builtin_amdgcn_mfma_f32_16x16x32_bf16(ahB, bfv[ct], accB[ct], 0, 0, 0);
                accB[ct] = __builtin_amdgcn_mfma_f32_16x16x32_bf16(alB, bfv[ct], accB[ct], 0, 0, 0);
            }
        }

        #pragma unroll
        for (int ct = 0; ct < 4; ++ct) {
            const int p = bx * 64 + ct * 16 + lm;
            #pragma unroll
            for (int reg = 0; reg < 4; ++reg) {
                const int oA = ot * 128 + w * 16 + quad * 4 + reg;
                const int ofsA = (b * 256 + oA) * 4096 + p;
                out_f[ofsA] = accA[ct][reg] + x[ofsA];
                const int ofsB = ofsA + 64 * 4096;
                out_f[ofsB] = accB[ct][reg] + x[ofsB];
            }
        }
    }
}

extern "C" void kernel_launch(void* const* d_in, const int* in_sizes, int n_in,
                              void* d_out, int out_size, void* d_ws, size_t ws_size,
                              hipStream_t stream) {
    const float* x       = (const float*)d_in[0];
    const float* w_phi   = (const float*)d_in[1];
    const float* w_theta = (const float*)d_in[2];
    const float* w_g     = (const float*)d_in[3];
    const float* w_mask  = (const float*)d_in[4];
    unsigned short* ws_u = (unsigned short*)d_ws;
    float* out_f = (float*)d_out;

    void* args[] = {
        (void*)&x, (void*)&w_phi, (void*)&w_theta, (void*)&w_g, (void*)&w_mask,
        (void*)&ws_u, (void*)&out_f
    };
    hipLaunchCooperativeKernel((const void*)mono_kernel, dim3(GRID), dim3(256),
                               args, 0, stream);
}